// Round 1
// baseline (246.280 us; speedup 1.0000x reference)
//
#include <hip/hip_runtime.h>

typedef unsigned short u16;
typedef unsigned int u32;
typedef u16 u16x8 __attribute__((ext_vector_type(8)));
typedef __bf16 bf16v8 __attribute__((ext_vector_type(8)));
typedef float f32x4 __attribute__((ext_vector_type(4)));
typedef float f32x2 __attribute__((ext_vector_type(2)));

#define DEV __device__ __forceinline__

DEV u16 f2bf(float f) {
  union { float f; u32 u; } v; v.f = f;
  u32 r = v.u + 0x7fffu + ((v.u >> 16) & 1u);
  return (u16)(r >> 16);
}
DEV float bf2f(u16 u) { union { u32 u; float f; } v; v.u = ((u32)u) << 16; return v.f; }

DEV f32x4 mfma16(u16x8 a, u16x8 b, f32x4 c) {
  return __builtin_amdgcn_mfma_f32_16x16x32_bf16(
      __builtin_bit_cast(bf16v8, a), __builtin_bit_cast(bf16v8, b), c, 0, 0, 0);
}

// ---------------- cast x (f32 -> bf16), 8 elems/thread ----------------
__global__ __launch_bounds__(256) void cast_x_kernel(const float* __restrict__ x,
                                                     u16* __restrict__ xb) {
  int i = blockIdx.x * 256 + threadIdx.x;  // 786432 threads total
  const f32x4* p = (const f32x4*)x;
  f32x4 a = p[2 * i], b = p[2 * i + 1];
  u16x8 o;
  #pragma unroll
  for (int j = 0; j < 4; ++j) { o[j] = f2bf(a[j]); o[4 + j] = f2bf(b[j]); }
  *((u16x8*)xb + i) = o;
}

// ---------------- pack weights to bf16, B^T ([N][K]) layouts ----------------
// wqkv_t [1152][384], wproj_t [384][384], w1_t [1536][384], w2_t [384][1536]
__global__ __launch_bounds__(256) void prep_w_kernel(
    const float* __restrict__ wq, const float* __restrict__ wk,
    const float* __restrict__ wv, const float* __restrict__ wproj,
    const float* __restrict__ w1, const float* __restrict__ w2,
    u16* __restrict__ wqkvt, u16* __restrict__ wprojt,
    u16* __restrict__ w1t, u16* __restrict__ w2t) {
  int idx = blockIdx.x * 256 + threadIdx.x;  // 1769472 total, exact
  if (idx < 442368) {
    int n = idx / 384, c = idx % 384;
    int which = n / 384;            // 0:q 1:k 2:v
    int hd = n % 384;
    int h = hd >> 6, d = hd & 63;
    const float* src = (which == 0) ? wq : ((which == 1) ? wk : wv);
    wqkvt[idx] = f2bf(src[((size_t)h * 384 + c) * 64 + d]);
  } else if (idx < 442368 + 147456) {
    int e = idx - 442368;
    int n = e / 384, c = e % 384;
    wprojt[e] = f2bf(wproj[(size_t)c * 384 + n]);
  } else if (idx < 442368 + 147456 + 589824) {
    int e = idx - (442368 + 147456);
    int n = e / 384, c = e % 384;
    w1t[e] = f2bf(w1[(size_t)c * 1536 + n]);
  } else {
    int e = idx - (442368 + 147456 + 589824);
    int n = e / 1536, c = e % 1536;
    w2t[e] = f2bf(w2[(size_t)c * 384 + n]);
  }
}

// ---------------- generic 128x128 bf16 MFMA GEMM, A[M][K] * Bt[N][K]^T ----------------
// EPI 0: bf16 store (qkv)         EPI 1: f32 store of acc + bias + f32 residual (proj)
// EPI 2: bf16 store of relu(acc+bias) (ff1)   EPI 3: f32 store of acc + bias + bf16 residual (ff2)
template <int K, int EPI>
__global__ __launch_bounds__(256) void gemm_kernel(
    const u16* __restrict__ A, const u16* __restrict__ Bt, const int N,
    const float* __restrict__ bias, const float* __restrict__ resf,
    const u16* __restrict__ resb, void* __restrict__ outv) {
  __shared__ u16 As[128 * 32];
  __shared__ u16 Bs[128 * 32];
  const int t = threadIdx.x;
  const int w = t >> 6, l = t & 63, l15 = l & 15, lg = l >> 4;
  const int wm = w >> 1, wn = w & 1;
  const int m0 = blockIdx.x * 128, n0 = blockIdx.y * 128;

  const int srow = t >> 1;          // 0..127
  const int scol = (t & 1) * 16;    // 0 or 16 (bf16 elems)
  const u16* ga = A + (size_t)(m0 + srow) * K + scol;
  const u16* gb = Bt + (size_t)(n0 + srow) * K + scol;

  f32x4 acc[4][4];
  #pragma unroll
  for (int i = 0; i < 4; ++i)
    #pragma unroll
    for (int j = 0; j < 4; ++j) acc[i][j] = (f32x4){0.f, 0.f, 0.f, 0.f};

  u16x8 ra0 = *(const u16x8*)ga, ra1 = *(const u16x8*)(ga + 8);
  u16x8 rb0 = *(const u16x8*)gb, rb1 = *(const u16x8*)(gb + 8);

  constexpr int NT = K / 32;
  #pragma unroll 1
  for (int kt = 0; kt < NT; ++kt) {
    *(u16x8*)&As[srow * 32 + scol] = ra0;
    *(u16x8*)&As[srow * 32 + scol + 8] = ra1;
    *(u16x8*)&Bs[srow * 32 + scol] = rb0;
    *(u16x8*)&Bs[srow * 32 + scol + 8] = rb1;
    __syncthreads();
    if (kt + 1 < NT) {  // prefetch next tile into registers (in flight across MFMAs)
      const u16* pa = ga + (kt + 1) * 32;
      const u16* pb = gb + (kt + 1) * 32;
      ra0 = *(const u16x8*)pa; ra1 = *(const u16x8*)(pa + 8);
      rb0 = *(const u16x8*)pb; rb1 = *(const u16x8*)(pb + 8);
    }
    u16x8 af[4], bfr[4];
    #pragma unroll
    for (int i = 0; i < 4; ++i) {
      af[i]  = *(const u16x8*)&As[(wm * 64 + i * 16 + l15) * 32 + lg * 8];
      bfr[i] = *(const u16x8*)&Bs[(wn * 64 + i * 16 + l15) * 32 + lg * 8];
    }
    #pragma unroll
    for (int mi = 0; mi < 4; ++mi)
      #pragma unroll
      for (int ni = 0; ni < 4; ++ni)
        acc[mi][ni] = mfma16(af[mi], bfr[ni], acc[mi][ni]);
    __syncthreads();
  }

  // epilogue: D row = (lg)*4 + r, col = l15 (verified C/D layout)
  #pragma unroll
  for (int mi = 0; mi < 4; ++mi) {
    #pragma unroll
    for (int ni = 0; ni < 4; ++ni) {
      const int rowg = m0 + wm * 64 + mi * 16 + lg * 4;
      const int colg = n0 + wn * 64 + ni * 16 + l15;
      float b_ = 0.f;
      if constexpr (EPI != 0) b_ = bias[colg];
      #pragma unroll
      for (int r = 0; r < 4; ++r) {
        float v = acc[mi][ni][r];
        const size_t oi = (size_t)(rowg + r) * N + colg;
        if constexpr (EPI == 0) {
          ((u16*)outv)[oi] = f2bf(v);
        } else if constexpr (EPI == 1) {
          ((float*)outv)[oi] = v + b_ + resf[oi];
        } else if constexpr (EPI == 2) {
          ((u16*)outv)[oi] = f2bf(fmaxf(v + b_, 0.f));
        } else {
          ((float*)outv)[oi] = v + b_ + bf2f(resb[oi]);
        }
      }
    }
  }
}

// ---------------- flash attention, causal, HS=64 ----------------
// qkv [B*T][1152]: cols 0..383 q (h*64+d), 384..767 k, 768..1151 v. out o [B*T][384].
// block = 4 waves; handles q-tiles {pair, 31-pair} of one (b,head). blockIdx%48 = head-lin -> XCD locality.
__global__ __launch_bounds__(256) void attn_kernel(const u16* __restrict__ qkv,
                                                   u16* __restrict__ o) {
  __shared__ u16 Kl[64 * 64];
  __shared__ u16 Vtl[64 * 64];
  __shared__ u16 Pl[4 * 16 * 64];

  const int t = threadIdx.x;
  const int w = t >> 6, l = t & 63, l15 = l & 15, lg = l >> 4;
  const int hl = blockIdx.x % 48;
  const int pair = blockIdx.x / 48;        // 0..15
  const int b = hl / 6, head = hl % 6;
  const size_t base = (size_t)b * 2048 * 1152;
  const int ss = t >> 3;                   // staging row 0..31
  const int d0 = (t & 7) * 8;

  #pragma unroll 1
  for (int which = 0; which < 2; ++which) {
    const int qt = which ? (31 - pair) : pair;
    // Q fragments (A-operand layout): row = l15, k contiguous
    u16x8 qf[2];
    {
      const u16* qp = qkv + base + (size_t)(qt * 64 + w * 16 + l15) * 1152 + head * 64 + lg * 8;
      qf[0] = *(const u16x8*)qp;
      qf[1] = *(const u16x8*)(qp + 32);
    }
    f32x4 Oa[4];
    float mr[4], lr[4];
    #pragma unroll
    for (int i = 0; i < 4; ++i) { Oa[i] = (f32x4){0.f, 0.f, 0.f, 0.f}; mr[i] = -3.0e38f; lr[i] = 0.f; }

    const int nkt = qt + 1;
    #pragma unroll 1
    for (int kt = 0; kt < nkt; ++kt) {
      // ---- stage K (swizzled) and V^T (swizzled) ----
      const u16* kp = qkv + base + (size_t)(kt * 64 + ss) * 1152 + 384 + head * 64 + d0;
      u16x8 kr0 = *(const u16x8*)kp;
      u16x8 kr1 = *(const u16x8*)(kp + (size_t)32 * 1152);
      u16x8 vr0 = *(const u16x8*)(kp + 384);
      u16x8 vr1 = *(const u16x8*)(kp + 384 + (size_t)32 * 1152);
      __syncthreads();  // prior tile's LDS reads done
      *(u16x8*)&Kl[ss * 64 + (d0 ^ ((ss & 7) << 3))] = kr0;
      {
        int s2 = ss + 32;
        *(u16x8*)&Kl[s2 * 64 + (d0 ^ ((s2 & 7) << 3))] = kr1;
      }
      #pragma unroll
      for (int j = 0; j < 8; ++j) {
        int dd = d0 + j;
        int X = ((dd & 7) ^ (dd >> 3)) << 3;   // per-row swizzle, free writes AND reads
        Vtl[dd * 64 + (ss ^ X)] = ((const u16*)&vr0)[j];
        Vtl[dd * 64 + ((ss + 32) ^ X)] = ((const u16*)&vr1)[j];
      }
      __syncthreads();

      // ---- S = Q K^T (per wave: 16 q-rows x 64 s) ----
      f32x4 sa[4];
      #pragma unroll
      for (int st = 0; st < 4; ++st) {
        sa[st] = (f32x4){0.f, 0.f, 0.f, 0.f};
        #pragma unroll
        for (int ks = 0; ks < 2; ++ks) {
          int sr = st * 16 + l15;
          u16x8 kf = *(const u16x8*)&Kl[sr * 64 + ((ks * 32 + lg * 8) ^ ((sr & 7) << 3))];
          sa[st] = mfma16(qf[ks], kf, sa[st]);
        }
      }
      // ---- scale + causal mask + online softmax ----
      const bool diag = (kt == qt);
      float pm[4] = {-3.0e38f, -3.0e38f, -3.0e38f, -3.0e38f};
      #pragma unroll
      for (int st = 0; st < 4; ++st)
        #pragma unroll
        for (int r = 0; r < 4; ++r) {
          float v = sa[st][r] * 0.125f;
          if (diag && (st * 16 + l15) > (w * 16 + lg * 4 + r)) v = -3.0e38f;
          sa[st][r] = v;
          pm[r] = fmaxf(pm[r], v);
        }
      #pragma unroll
      for (int m = 1; m < 16; m <<= 1)
        #pragma unroll
        for (int r = 0; r < 4; ++r) pm[r] = fmaxf(pm[r], __shfl_xor(pm[r], m, 16));
      float sc[4];
      #pragma unroll
      for (int r = 0; r < 4; ++r) {
        float mn = fmaxf(mr[r], pm[r]);
        sc[r] = __expf(mr[r] - mn);
        mr[r] = mn;
      }
      float rs[4] = {0.f, 0.f, 0.f, 0.f};
      #pragma unroll
      for (int st = 0; st < 4; ++st)
        #pragma unroll
        for (int r = 0; r < 4; ++r) {
          float p = __expf(sa[st][r] - mr[r]);
          rs[r] += p;
          int q_ = lg * 4 + r, s_ = st * 16 + l15;
          Pl[w * 1024 + q_ * 64 + (s_ ^ ((q_ & 7) << 3))] = f2bf(p);
        }
      #pragma unroll
      for (int m = 1; m < 16; m <<= 1)
        #pragma unroll
        for (int r = 0; r < 4; ++r) rs[r] += __shfl_xor(rs[r], m, 16);
      #pragma unroll
      for (int r = 0; r < 4; ++r) lr[r] = lr[r] * sc[r] + rs[r];
      #pragma unroll
      for (int dt = 0; dt < 4; ++dt)
        #pragma unroll
        for (int r = 0; r < 4; ++r) Oa[dt][r] *= sc[r];

      // ---- O += P V ----
      #pragma unroll
      for (int dt = 0; dt < 4; ++dt)
        #pragma unroll
        for (int ks = 0; ks < 2; ++ks) {
          u16x8 pf = *(const u16x8*)&Pl[w * 1024 + l15 * 64 + ((ks * 32 + lg * 8) ^ ((l15 & 7) << 3))];
          int dd = dt * 16 + l15;
          int X = ((dd & 7) ^ (dd >> 3)) << 3;
          u16x8 vf = *(const u16x8*)&Vtl[dd * 64 + ((ks * 32 + lg * 8) ^ X)];
          Oa[dt] = mfma16(pf, vf, Oa[dt]);
        }
    }  // kt

    // ---- writeout ----
    float inv[4];
    #pragma unroll
    for (int r = 0; r < 4; ++r) inv[r] = 1.0f / lr[r];
    #pragma unroll
    for (int dt = 0; dt < 4; ++dt)
      #pragma unroll
      for (int r = 0; r < 4; ++r) {
        size_t row = (size_t)b * 2048 + qt * 64 + w * 16 + lg * 4 + r;
        o[row * 384 + head * 64 + dt * 16 + l15] = f2bf(Oa[dt][r] * inv[r]);
      }
  }  // which
}

// ---------------- layernorm (wave per row of 384) ----------------
// OUT_BF16=1 -> bf16 out (x1), OUT_BF16=0 -> f32 out (final)
template <int OUT_BF16>
__global__ __launch_bounds__(256) void ln_kernel(const float* __restrict__ in,
                                                 const float* __restrict__ g,
                                                 const float* __restrict__ be,
                                                 void* __restrict__ outv) {
  const int row = blockIdx.x * 4 + (threadIdx.x >> 6);
  const int lane = threadIdx.x & 63;
  const float* p = in + (size_t)row * 384 + lane * 6;
  float v[6];
  {
    const f32x2* p2 = (const f32x2*)p;
    f32x2 a0 = p2[0], a1 = p2[1], a2 = p2[2];
    v[0] = a0[0]; v[1] = a0[1]; v[2] = a1[0]; v[3] = a1[1]; v[4] = a2[0]; v[5] = a2[1];
  }
  float s = v[0] + v[1] + v[2] + v[3] + v[4] + v[5];
  #pragma unroll
  for (int m = 1; m < 64; m <<= 1) s += __shfl_xor(s, m, 64);
  const float mu = s * (1.0f / 384.0f);
  float d2 = 0.f;
  #pragma unroll
  for (int j = 0; j < 6; ++j) { float d = v[j] - mu; d2 += d * d; }
  #pragma unroll
  for (int m = 1; m < 64; m <<= 1) d2 += __shfl_xor(d2, m, 64);
  const float rstd = rsqrtf(d2 * (1.0f / 384.0f) + 1e-5f);
  const int c = lane * 6;
  float y[6];
  #pragma unroll
  for (int j = 0; j < 6; ++j) y[j] = (v[j] - mu) * rstd * g[c + j] + be[c + j];
  if constexpr (OUT_BF16) {
    u32* ob = (u32*)((u16*)outv + (size_t)row * 384 + c);
    #pragma unroll
    for (int j = 0; j < 3; ++j)
      ob[j] = (u32)f2bf(y[2 * j]) | ((u32)f2bf(y[2 * j + 1]) << 16);
  } else {
    float* of = (float*)outv + (size_t)row * 384 + c;
    f32x2* o2 = (f32x2*)of;
    #pragma unroll
    for (int j = 0; j < 3; ++j) o2[j] = (f32x2){y[2 * j], y[2 * j + 1]};
  }
}

// ---------------- launch ----------------
extern "C" void kernel_launch(void* const* d_in, const int* in_sizes, int n_in,
                              void* d_out, int out_size, void* d_ws, size_t ws_size,
                              hipStream_t stream) {
  const float* x     = (const float*)d_in[0];
  const float* wq    = (const float*)d_in[1];
  const float* wk    = (const float*)d_in[2];
  const float* wv    = (const float*)d_in[3];
  const float* wproj = (const float*)d_in[4];
  const float* bproj = (const float*)d_in[5];
  const float* w1    = (const float*)d_in[6];
  const float* b1    = (const float*)d_in[7];
  const float* w2    = (const float*)d_in[8];
  const float* b2    = (const float*)d_in[9];
  const float* g1    = (const float*)d_in[10];
  const float* be1   = (const float*)d_in[11];
  const float* g2    = (const float*)d_in[12];
  const float* be2   = (const float*)d_in[13];

  char* ws = (char*)d_ws;
  u16*   xb    = (u16*)(ws + 0);                    // 12,582,912 B
  u16*   qkv   = (u16*)(ws + 12582912);             // 37,748,736 B
  u16*   obuf  = (u16*)(ws + 50331648);             // 12,582,912 B
  float* res1  = (float*)(ws + 62914560);           // 25,165,824 B
  u16*   x1b   = (u16*)(ws + 88080384);             // 12,582,912 B
  u16*   wqkvt = (u16*)(ws + 100663296);            //    884,736 B
  u16*   wprjt = (u16*)(ws + 101548032);            //    294,912 B
  u16*   w1t   = (u16*)(ws + 101842944);            //  1,179,648 B
  u16*   w2t   = (u16*)(ws + 103022592);            //  1,179,648 B
  u16*   h1    = qkv;  // alias: spans qkv+obuf (50,331,648 B), both dead by FF1

  cast_x_kernel<<<3072, 256, 0, stream>>>(x, xb);
  prep_w_kernel<<<6912, 256, 0, stream>>>(wq, wk, wv, wproj, w1, w2, wqkvt, wprjt, w1t, w2t);
  // QKV: [16384,384] x [384,1152]
  gemm_kernel<384, 0><<<dim3(128, 9), 256, 0, stream>>>(xb, wqkvt, 1152, nullptr, nullptr, nullptr, qkv);
  // attention
  attn_kernel<<<768, 256, 0, stream>>>(qkv, obuf);
  // proj + bias + x residual -> res1 (f32)
  gemm_kernel<384, 1><<<dim3(128, 3), 256, 0, stream>>>(obuf, wprjt, 384, bproj, x, nullptr, res1);
  // LN1 -> x1 (bf16)
  ln_kernel<1><<<4096, 256, 0, stream>>>(res1, g1, be1, x1b);
  // FF1: relu(x1 @ w1 + b1) -> h1 (bf16)
  gemm_kernel<384, 2><<<dim3(128, 12), 256, 0, stream>>>(x1b, w1t, 1536, b1, nullptr, nullptr, h1);
  // FF2: h1 @ w2 + b2 + x1 residual -> res1 (f32, reuse)
  gemm_kernel<1536, 3><<<dim3(128, 3), 256, 0, stream>>>(h1, w2t, 384, b2, nullptr, x1b, res1);
  // LN2 -> out (f32)
  ln_kernel<0><<<4096, 256, 0, stream>>>(res1, g2, be2, d_out);
}

// Round 2
// 234.427 us; speedup vs baseline: 1.0506x; 1.0506x over previous
//
#include <hip/hip_runtime.h>

typedef unsigned short u16;
typedef unsigned int u32;
typedef u16 u16x8 __attribute__((ext_vector_type(8)));
typedef u32 u32x4 __attribute__((ext_vector_type(4)));
typedef __bf16 bf16v8 __attribute__((ext_vector_type(8)));
typedef float f32x4 __attribute__((ext_vector_type(4)));
typedef float f32x2 __attribute__((ext_vector_type(2)));

#define DEV __device__ __forceinline__

DEV u16 f2bf(float f) {
  union { float f; u32 u; } v; v.f = f;
  u32 r = v.u + 0x7fffu + ((v.u >> 16) & 1u);
  return (u16)(r >> 16);
}
DEV float bf2f(u16 u) { union { u32 u; float f; } v; v.u = ((u32)u) << 16; return v.f; }

DEV u32 cvtpk(float a, float b) {  // bf16(a) in lo16, bf16(b) in hi16
  u32 d;
  asm("v_cvt_pk_bf16_f32 %0, %1, %2" : "=v"(d) : "v"(a), "v"(b));
  return d;
}

DEV f32x4 mfma16(u16x8 a, u16x8 b, f32x4 c) {
  return __builtin_amdgcn_mfma_f32_16x16x32_bf16(
      __builtin_bit_cast(bf16v8, a), __builtin_bit_cast(bf16v8, b), c, 0, 0, 0);
}

typedef const __attribute__((address_space(1))) void* gas_ptr;
typedef __attribute__((address_space(3))) void* las_ptr;
#define GLOAD16(GP, LP) __builtin_amdgcn_global_load_lds((gas_ptr)(GP), (las_ptr)(LP), 16, 0, 0)

// ---------------- cast x (f32 -> bf16), 8 elems/thread ----------------
__global__ __launch_bounds__(256) void cast_x_kernel(const float* __restrict__ x,
                                                     u16* __restrict__ xb) {
  int i = blockIdx.x * 256 + threadIdx.x;
  const f32x4* p = (const f32x4*)x;
  f32x4 a = p[2 * i], b = p[2 * i + 1];
  u16x8 o;
  #pragma unroll
  for (int j = 0; j < 4; ++j) { o[j] = f2bf(a[j]); o[4 + j] = f2bf(b[j]); }
  *((u16x8*)xb + i) = o;
}

// ---------------- pack weights to bf16, B^T ([N][K]) layouts ----------------
__global__ __launch_bounds__(256) void prep_w_kernel(
    const float* __restrict__ wq, const float* __restrict__ wk,
    const float* __restrict__ wv, const float* __restrict__ wproj,
    const float* __restrict__ w1, const float* __restrict__ w2,
    u16* __restrict__ wqkvt, u16* __restrict__ wprojt,
    u16* __restrict__ w1t, u16* __restrict__ w2t) {
  int idx = blockIdx.x * 256 + threadIdx.x;  // 1769472 total, exact
  if (idx < 442368) {
    int n = idx / 384, c = idx % 384;
    int which = n / 384;
    int hd = n % 384;
    int h = hd >> 6, d = hd & 63;
    const float* src = (which == 0) ? wq : ((which == 1) ? wk : wv);
    wqkvt[idx] = f2bf(src[((size_t)h * 384 + c) * 64 + d]);
  } else if (idx < 442368 + 147456) {
    int e = idx - 442368;
    int n = e / 384, c = e % 384;
    wprojt[e] = f2bf(wproj[(size_t)c * 384 + n]);
  } else if (idx < 442368 + 147456 + 589824) {
    int e = idx - (442368 + 147456);
    int n = e / 384, c = e % 384;
    w1t[e] = f2bf(w1[(size_t)c * 1536 + n]);
  } else {
    int e = idx - (442368 + 147456 + 589824);
    int n = e / 1536, c = e % 1536;
    w2t[e] = f2bf(w2[(size_t)c * 384 + n]);
  }
}

// ---------------- GEMM: A[M][K]*Bt[N][K]^T, m97-style global_load_lds staging ----------------
// BM=128: 4 waves 2x2, acc[4][4].  BM=64: 4 waves 1x4, acc[4][2].
// EPI 0: bf16 (qkv)  1: f32 acc+bias+f32res (proj)  2: bf16 relu(acc+bias) (ff1)
// EPI 3: f32 acc+bias+bf16res (ff2)
template <int K, int BM, int EPI>
__global__ __launch_bounds__(256) void gemm_kernel(
    const u16* __restrict__ A, const u16* __restrict__ Bt, const int N,
    const float* __restrict__ bias, const float* __restrict__ resf,
    const u16* __restrict__ resb, void* __restrict__ outv) {
  constexpr int NF = (BM == 128) ? 4 : 2;
  constexpr int ACALLS = BM / 64;
  __shared__ u16 As[BM * 32];
  __shared__ u16 Bs[128 * 32];
  const int t = threadIdx.x;
  const int w = t >> 6, l = t & 63, l15 = l & 15, lg = l >> 4;
  const int wrow = (BM == 128) ? (w >> 1) * 64 : 0;
  const int wcol = (BM == 128) ? (w & 1) * 64 : w * 32;
  const int m0 = blockIdx.x * BM, n0 = blockIdx.y * 128;

  const int lrow = l >> 2, lcol = (l & 3) * 8;
  const u16* gA = A + (size_t)(m0 + lrow) * K + lcol;
  const u16* gB = Bt + (size_t)(n0 + lrow) * K + lcol;

  f32x4 acc[4][NF];
  #pragma unroll
  for (int i = 0; i < 4; ++i)
    #pragma unroll
    for (int j = 0; j < NF; ++j) acc[i][j] = (f32x4){0.f, 0.f, 0.f, 0.f};

  constexpr int NT = K / 32;
  #pragma unroll 1
  for (int kt = 0; kt < NT; ++kt) {
    #pragma unroll
    for (int c = 0; c < ACALLS; ++c)
      GLOAD16(gA + (size_t)(w * (BM / 4) + c * 16) * K + kt * 32,
              (char*)As + w * (BM * 16) + c * 1024);
    #pragma unroll
    for (int c = 0; c < 2; ++c)
      GLOAD16(gB + (size_t)(w * 32 + c * 16) * K + kt * 32,
              (char*)Bs + w * 2048 + c * 1024);
    __syncthreads();
    u16x8 af[4], bfr[NF];
    #pragma unroll
    for (int i = 0; i < 4; ++i)
      af[i] = *(const u16x8*)&As[(wrow + i * 16 + l15) * 32 + lg * 8];
    #pragma unroll
    for (int j = 0; j < NF; ++j)
      bfr[j] = *(const u16x8*)&Bs[(wcol + j * 16 + l15) * 32 + lg * 8];
    #pragma unroll
    for (int mi = 0; mi < 4; ++mi)
      #pragma unroll
      for (int ni = 0; ni < NF; ++ni)
        acc[mi][ni] = mfma16(af[mi], bfr[ni], acc[mi][ni]);
    __syncthreads();
  }

  #pragma unroll
  for (int mi = 0; mi < 4; ++mi) {
    #pragma unroll
    for (int ni = 0; ni < NF; ++ni) {
      const int rowg = m0 + wrow + mi * 16 + lg * 4;
      const int colg = n0 + wcol + ni * 16 + l15;
      float b_ = 0.f;
      if constexpr (EPI != 0) b_ = bias[colg];
      #pragma unroll
      for (int r = 0; r < 4; ++r) {
        float v = acc[mi][ni][r];
        const size_t oi = (size_t)(rowg + r) * N + colg;
        if constexpr (EPI == 0) {
          ((u16*)outv)[oi] = f2bf(v);
        } else if constexpr (EPI == 1) {
          ((float*)outv)[oi] = v + b_ + resf[oi];
        } else if constexpr (EPI == 2) {
          ((u16*)outv)[oi] = f2bf(fmaxf(v + b_, 0.f));
        } else {
          ((float*)outv)[oi] = v + b_ + bf2f(resb[oi]);
        }
      }
    }
  }
}

// ---------------- flash attention, causal, HS=64, swapped-QK^T ----------------
// grid = 1536: qt = 31 - blockIdx/48 (heavy first), hl = blockIdx%48 (head pinned to XCD).
// 4 waves x 16 q-rows. Lane state: softmax per q=l15 (S^T layout); O rows q=lg*4+r.
__global__ __launch_bounds__(256) void attn_kernel(const u16* __restrict__ qkv,
                                                   u16* __restrict__ o) {
  __shared__ u16 Kl[64 * 64];
  __shared__ u16 Vtl[64 * 64];

  const int t = threadIdx.x;
  const int w = t >> 6, l = t & 63, l15 = l & 15, lg = l >> 4;
  const int qt = 31 - blockIdx.x / 48;
  const int hl = blockIdx.x % 48;
  const int b = hl / 6, head = hl % 6;
  const size_t base = (size_t)b * 2048 * 1152;
  const int ss = t >> 3;            // staging row 0..31
  const int d0 = (t & 7) * 8;
  const float SC = 0.125f * 1.44269504f;  // fold 1/sqrt(64) into exp2 domain

  // Q fragments (B-operand: row=q=l15, k contiguous)
  u16x8 qf[2];
  {
    const u16* qp = qkv + base + (size_t)(qt * 64 + w * 16 + l15) * 1152 + head * 64 + lg * 8;
    qf[0] = *(const u16x8*)qp;
    qf[1] = *(const u16x8*)(qp + 32);
  }
  f32x4 Oa[4];
  #pragma unroll
  for (int i = 0; i < 4; ++i) Oa[i] = (f32x4){0.f, 0.f, 0.f, 0.f};
  float m_l = -3.0e38f, l_l = 0.f;

  #pragma unroll 1
  for (int kt = 0; kt <= qt; ++kt) {
    // ---- stage K (XOR-swizzled rows) and V^T (swizzled) ----
    const u16* kp = qkv + base + (size_t)(kt * 64 + ss) * 1152 + 384 + head * 64 + d0;
    u16x8 kr0 = *(const u16x8*)kp;
    u16x8 kr1 = *(const u16x8*)(kp + (size_t)32 * 1152);
    u16x8 vr0 = *(const u16x8*)(kp + 384);
    u16x8 vr1 = *(const u16x8*)(kp + 384 + (size_t)32 * 1152);
    __syncthreads();  // prior tile's LDS reads done
    *(u16x8*)&Kl[ss * 64 + (d0 ^ ((ss & 7) << 3))] = kr0;
    {
      int s2 = ss + 32;
      *(u16x8*)&Kl[s2 * 64 + (d0 ^ ((s2 & 7) << 3))] = kr1;
    }
    #pragma unroll
    for (int j = 0; j < 8; ++j) {
      int dd = d0 + j;
      int X = ((dd & 7) ^ (dd >> 3)) << 3;
      Vtl[dd * 64 + (ss ^ X)] = ((const u16*)&vr0)[j];
      Vtl[dd * 64 + ((ss + 32) ^ X)] = ((const u16*)&vr1)[j];
    }
    __syncthreads();

    // ---- S^T = K Q^T : lane holds S[s=st*16+lg*4+r][q=l15] ----
    f32x4 sa[4];
    #pragma unroll
    for (int st = 0; st < 4; ++st) {
      sa[st] = (f32x4){0.f, 0.f, 0.f, 0.f};
      #pragma unroll
      for (int ks = 0; ks < 2; ++ks) {
        int sr = st * 16 + l15;
        u16x8 kf = *(const u16x8*)&Kl[sr * 64 + ((ks * 32 + lg * 8) ^ ((sr & 7) << 3))];
        sa[st] = mfma16(kf, qf[ks], sa[st]);
      }
    }
    if (kt == qt) {  // causal mask on diagonal tile only
      #pragma unroll
      for (int st = 0; st < 4; ++st)
        #pragma unroll
        for (int r = 0; r < 4; ++r)
          if (st * 16 + lg * 4 + r > w * 16 + l15) sa[st][r] = -3.0e38f;
    }
    // ---- row max: in-lane over 16 + xor16/32 across lg ----
    float pm = sa[0][0];
    #pragma unroll
    for (int st = 0; st < 4; ++st)
      #pragma unroll
      for (int r = 0; r < 4; ++r) pm = fmaxf(pm, sa[st][r]);
    pm = fmaxf(pm, __shfl_xor(pm, 16));
    pm = fmaxf(pm, __shfl_xor(pm, 32));
    float mn = fmaxf(m_l, pm);
    float sc = exp2f((m_l - mn) * SC);
    m_l = mn;
    // ---- p = exp2((s-m)*SC), pack to bf16 pairs, row-sum ----
    u32 pk2[4][2];
    float rs = 0.f;
    #pragma unroll
    for (int st = 0; st < 4; ++st) {
      float p0 = exp2f((sa[st][0] - mn) * SC);
      float p1 = exp2f((sa[st][1] - mn) * SC);
      float p2 = exp2f((sa[st][2] - mn) * SC);
      float p3 = exp2f((sa[st][3] - mn) * SC);
      rs += (p0 + p1) + (p2 + p3);
      pk2[st][0] = cvtpk(p0, p1);
      pk2[st][1] = cvtpk(p2, p3);
    }
    rs += __shfl_xor(rs, 16);
    rs += __shfl_xor(rs, 32);
    l_l = l_l * sc + rs;
    // ---- rescale O (rows q=lg*4+r: fetch that row's sc) ----
    float scq[4];
    #pragma unroll
    for (int r = 0; r < 4; ++r) scq[r] = __shfl(sc, lg * 4 + r, 16);
    #pragma unroll
    for (int dt = 0; dt < 4; ++dt)
      #pragma unroll
      for (int r = 0; r < 4; ++r) Oa[dt][r] *= scq[r];

    // ---- O += P V : P-fragments via in-register shuffle transpose ----
    #pragma unroll
    for (int ks = 0; ks < 2; ++ks) {
      u32 wds[4];
      #pragma unroll
      for (int wd = 0; wd < 4; ++wd) {
        int src = ((2 * (lg & 1) + (wd >> 1)) << 4) | l15;
        u32 c0 = (u32)__shfl((int)pk2[2 * ks][wd & 1], src);
        u32 c1 = (u32)__shfl((int)pk2[2 * ks + 1][wd & 1], src);
        wds[wd] = (lg & 2) ? c1 : c0;
      }
      u16x8 pf = __builtin_bit_cast(u16x8, (u32x4){wds[0], wds[1], wds[2], wds[3]});
      #pragma unroll
      for (int dt = 0; dt < 4; ++dt) {
        int dd = dt * 16 + l15;
        int X = ((dd & 7) ^ (dd >> 3)) << 3;
        u16x8 vf = *(const u16x8*)&Vtl[dd * 64 + ((ks * 32 + lg * 8) ^ X)];
        Oa[dt] = mfma16(pf, vf, Oa[dt]);
      }
    }
  }  // kt

  // ---- writeout: O rows q=lg*4+r need that row's 1/l ----
  float inv = 1.0f / l_l;
  float invq[4];
  #pragma unroll
  for (int r = 0; r < 4; ++r) invq[r] = __shfl(inv, lg * 4 + r, 16);
  #pragma unroll
  for (int dt = 0; dt < 4; ++dt)
    #pragma unroll
    for (int r = 0; r < 4; ++r) {
      size_t row = (size_t)b * 2048 + qt * 64 + w * 16 + lg * 4 + r;
      o[row * 384 + head * 64 + dt * 16 + l15] = f2bf(Oa[dt][r] * invq[r]);
    }
}

// ---------------- layernorm (wave per row of 384) ----------------
template <int OUT_BF16>
__global__ __launch_bounds__(256) void ln_kernel(const float* __restrict__ in,
                                                 const float* __restrict__ g,
                                                 const float* __restrict__ be,
                                                 void* __restrict__ outv) {
  const int row = blockIdx.x * 4 + (threadIdx.x >> 6);
  const int lane = threadIdx.x & 63;
  const float* p = in + (size_t)row * 384 + lane * 6;
  float v[6];
  {
    const f32x2* p2 = (const f32x2*)p;
    f32x2 a0 = p2[0], a1 = p2[1], a2 = p2[2];
    v[0] = a0[0]; v[1] = a0[1]; v[2] = a1[0]; v[3] = a1[1]; v[4] = a2[0]; v[5] = a2[1];
  }
  float s = v[0] + v[1] + v[2] + v[3] + v[4] + v[5];
  #pragma unroll
  for (int m = 1; m < 64; m <<= 1) s += __shfl_xor(s, m, 64);
  const float mu = s * (1.0f / 384.0f);
  float d2 = 0.f;
  #pragma unroll
  for (int j = 0; j < 6; ++j) { float d = v[j] - mu; d2 += d * d; }
  #pragma unroll
  for (int m = 1; m < 64; m <<= 1) d2 += __shfl_xor(d2, m, 64);
  const float rstd = rsqrtf(d2 * (1.0f / 384.0f) + 1e-5f);
  const int c = lane * 6;
  float y[6];
  #pragma unroll
  for (int j = 0; j < 6; ++j) y[j] = (v[j] - mu) * rstd * g[c + j] + be[c + j];
  if constexpr (OUT_BF16) {
    u32* ob = (u32*)((u16*)outv + (size_t)row * 384 + c);
    #pragma unroll
    for (int j = 0; j < 3; ++j)
      ob[j] = (u32)f2bf(y[2 * j]) | ((u32)f2bf(y[2 * j + 1]) << 16);
  } else {
    float* of = (float*)outv + (size_t)row * 384 + c;
    f32x2* o2 = (f32x2*)of;
    #pragma unroll
    for (int j = 0; j < 3; ++j) o2[j] = (f32x2){y[2 * j], y[2 * j + 1]};
  }
}

// ---------------- launch ----------------
extern "C" void kernel_launch(void* const* d_in, const int* in_sizes, int n_in,
                              void* d_out, int out_size, void* d_ws, size_t ws_size,
                              hipStream_t stream) {
  const float* x     = (const float*)d_in[0];
  const float* wq    = (const float*)d_in[1];
  const float* wk    = (const float*)d_in[2];
  const float* wv    = (const float*)d_in[3];
  const float* wproj = (const float*)d_in[4];
  const float* bproj = (const float*)d_in[5];
  const float* w1    = (const float*)d_in[6];
  const float* b1    = (const float*)d_in[7];
  const float* w2    = (const float*)d_in[8];
  const float* b2    = (const float*)d_in[9];
  const float* g1    = (const float*)d_in[10];
  const float* be1   = (const float*)d_in[11];
  const float* g2    = (const float*)d_in[12];
  const float* be2   = (const float*)d_in[13];

  char* ws = (char*)d_ws;
  u16*   xb    = (u16*)(ws + 0);
  u16*   qkv   = (u16*)(ws + 12582912);
  u16*   obuf  = (u16*)(ws + 50331648);
  float* res1  = (float*)(ws + 62914560);
  u16*   x1b   = (u16*)(ws + 88080384);
  u16*   wqkvt = (u16*)(ws + 100663296);
  u16*   wprjt = (u16*)(ws + 101548032);
  u16*   w1t   = (u16*)(ws + 101842944);
  u16*   w2t   = (u16*)(ws + 103022592);
  u16*   h1    = qkv;  // alias: qkv+obuf dead by FF1

  cast_x_kernel<<<3072, 256, 0, stream>>>(x, xb);
  prep_w_kernel<<<6912, 256, 0, stream>>>(wq, wk, wv, wproj, w1, w2, wqkvt, wprjt, w1t, w2t);
  gemm_kernel<384, 128, 0><<<dim3(128, 9), 256, 0, stream>>>(xb, wqkvt, 1152, nullptr, nullptr, nullptr, qkv);
  attn_kernel<<<1536, 256, 0, stream>>>(qkv, obuf);
  gemm_kernel<384, 64, 1><<<dim3(256, 3), 256, 0, stream>>>(obuf, wprjt, 384, bproj, x, nullptr, res1);
  ln_kernel<1><<<4096, 256, 0, stream>>>(res1, g1, be1, x1b);
  gemm_kernel<384, 128, 2><<<dim3(128, 12), 256, 0, stream>>>(x1b, w1t, 1536, b1, nullptr, nullptr, h1);
  gemm_kernel<1536, 64, 3><<<dim3(256, 3), 256, 0, stream>>>(h1, w2t, 384, b2, nullptr, x1b, res1);
  ln_kernel<0><<<4096, 256, 0, stream>>>(res1, g2, be2, d_out);
}